// Round 10
// baseline (33.969 us; speedup 1.0000x reference)
//
#include <hip/hip_runtime.h>

typedef float f4 __attribute__((ext_vector_type(4)));

// R8 + deferred batched softmax + block-level W staging.
// One wave per 8 tokens (4 ILP-2 pairs). Lane i owns d {4i+256c, c=0..3}:
// dwordx4, 1KB/instr coalesced. W staged fp32 to LDS once per block (one
// barrier), each wave fills 144 weight regs from LDS (conflict-free b128).
// Main loop: prefetch next pair -> 288 FMA -> 9-way-ILP DPP reduce ->
// readlane broadcast + cndmask stash (lane t collects token t's 9 sums).
// Softmax for all 8 tokens runs ONCE, in parallel on lanes 0..7, after the
// loop -- the serial softmax chain is off the per-pair critical path.
// NOTE: never raise min-waves in __launch_bounds__ (R3: weight remat).
#define TPW 8

template <int CTRL>
__device__ __forceinline__ float dpp_add(float x) {
  int yi = __builtin_amdgcn_update_dpp(0, __float_as_int(x), CTRL, 0xF, 0xF, true);
  return x + __int_as_float(yi);
}

// After this, lane 63 holds the full 64-lane sum.
__device__ __forceinline__ float wave_sum63(float x) {
  x = dpp_add<0x111>(x);  // row_shr:1
  x = dpp_add<0x112>(x);  // row_shr:2
  x = dpp_add<0x114>(x);  // row_shr:4
  x = dpp_add<0x118>(x);  // row_shr:8
  x = dpp_add<0x142>(x);  // row_bcast:15
  x = dpp_add<0x143>(x);  // row_bcast:31
  return x;
}

__global__ __launch_bounds__(256, 2)
void moa_kernel(const float* __restrict__ tok,
                const float* __restrict__ Wq,
                const float* __restrict__ Wk,
                const float* __restrict__ Wv,
                float* __restrict__ out) {
  __shared__ __align__(16) float wlds[9 * 1024];   // 36 KB
  const int tid = threadIdx.x;

  // ---- stage W to LDS once per block (coalesced, 9 f4 per thread) ----
  {
    const float* Wsrc[3] = {Wq, Wk, Wv};
#pragma unroll
    for (int r = 0; r < 9; ++r) {
      const int idx = r * 256 + tid;       // f4 index 0..2303
      const int j   = idx >> 8;            // expert row 0..8
      const int k4  = idx & 255;
      *(f4*)(wlds + j * 1024 + k4 * 4) =
          *(const f4*)(Wsrc[j / 3] + (j % 3) * 1024 + k4 * 4);
    }
  }
  __syncthreads();

  const int lane = tid & 63;
  const int wid  = (blockIdx.x << 2) | (tid >> 6);
  const int base = lane << 2;

  // ---- fill 144 weight regs from LDS (36x ds_read_b128, conflict-free) ----
  f4 w[9][4];
#pragma unroll
  for (int j = 0; j < 9; ++j)
#pragma unroll
    for (int c = 0; c < 4; ++c)
      w[j][c] = *(const f4*)(wlds + j * 1024 + c * 256 + base);

  const int t0 = wid * TPW;
  const float* wbase = tok + (size_t)t0 * 1024 + base;

  // ---- prologue: load pair 0 ----
  f4 xa[2][4], xb[2][4];
#pragma unroll
  for (int p = 0; p < 2; ++p)
#pragma unroll
    for (int c = 0; c < 4; ++c)
      xa[p][c] = *(const f4*)(wbase + (size_t)p * 1024 + c * 256);

  // distributed result file: lane t will hold token t0+t's 9 sums
  float dst[9];
#pragma unroll
  for (int j = 0; j < 9; ++j) dst[j] = 0.0f;

#pragma unroll
  for (int i = 0; i < TPW / 2; ++i) {          // 4 pairs
    f4 (&cur)[2][4] = (i & 1) ? xb : xa;       // compile-time after unroll
    f4 (&nxt)[2][4] = (i & 1) ? xa : xb;

    // issue next pair's 8 loads before any compute
    if (i < TPW / 2 - 1) {
#pragma unroll
      for (int p = 0; p < 2; ++p)
#pragma unroll
        for (int c = 0; c < 4; ++c)
          nxt[p][c] = *(const f4*)(wbase + (size_t)(2 * (i + 1) + p) * 1024 + c * 256);
    }

    // ---- two independent dot blocks ----
    float sA[9], sB[9];
#pragma unroll
    for (int j = 0; j < 9; ++j) {
      f4 a = cur[0][0] * w[j][0];
      a += cur[0][1] * w[j][1];
      a += cur[0][2] * w[j][2];
      a += cur[0][3] * w[j][3];
      sA[j] = (a.x + a.y) + (a.z + a.w);
      f4 b = cur[1][0] * w[j][0];
      b += cur[1][1] * w[j][1];
      b += cur[1][2] * w[j][2];
      b += cur[1][3] * w[j][3];
      sB[j] = (b.x + b.y) + (b.z + b.w);
    }

    // ---- 18 interleaved DPP chains (9-way ILP each token) ----
#pragma unroll
    for (int j = 0; j < 9; ++j) {
      sA[j] = wave_sum63(sA[j]);
      sB[j] = wave_sum63(sB[j]);
    }

    // ---- stash lane-63 sums into distributed file (lane 2i / 2i+1) ----
#pragma unroll
    for (int j = 0; j < 9; ++j) {
      float a63 = __int_as_float(__builtin_amdgcn_readlane(__float_as_int(sA[j]), 63));
      float b63 = __int_as_float(__builtin_amdgcn_readlane(__float_as_int(sB[j]), 63));
      dst[j] = (lane == 2 * i)     ? a63 : dst[j];
      dst[j] = (lane == 2 * i + 1) ? b63 : dst[j];
    }
  }

  // ---- batched epilogue: 8 parallel softmaxes on lanes 0..7 ----
  if (lane < TPW) {
    float r[9];
#pragma unroll
    for (int j = 0; j < 9; ++j) r[j] = dst[j];
    // q=r[0..2], k=r[3..5], v=r[6..8]
    float lg[3];
#pragma unroll
    for (int e = 0; e < 3; ++e) {
      float e0 = __expf(r[e] * r[3]);
      float e1 = __expf(r[e] * r[4]);
      float e2 = __expf(r[e] * r[5]);
      float den = (e0 + e1) + e2;
      float num = e0 * r[6] + e1 * r[7] + e2 * r[8];
      lg[e] = num * __builtin_amdgcn_rcpf(den);
    }
    float u0 = __expf(lg[0]);
    float u1 = __expf(lg[1]);
    float u2 = __expf(lg[2]);
    float rs = __builtin_amdgcn_rcpf((u0 + u1) + u2);
    float* op = out + (size_t)(t0 + lane) * 3;
    op[0] = u0 * rs;
    op[1] = u1 * rs;
    op[2] = u2 * rs;
  }
}

extern "C" void kernel_launch(void* const* d_in, const int* in_sizes, int n_in,
                              void* d_out, int out_size, void* d_ws, size_t ws_size,
                              hipStream_t stream) {
  const float* tok = (const float*)d_in[0];
  const float* Wq  = (const float*)d_in[1];
  const float* Wk  = (const float*)d_in[2];
  const float* Wv  = (const float*)d_in[3];
  float* out = (float*)d_out;

  const int n_tokens = in_sizes[0] / 1024;   // 32768
  const int waves    = n_tokens / TPW;       // 4096
  const int blocks   = waves / 4;            // 1024

  hipLaunchKernelGGL(moa_kernel, dim3(blocks), dim3(256), 0, stream,
                     tok, Wq, Wk, Wv, out);
}

// Round 11
// 27.414 us; speedup vs baseline: 1.2391x; 1.2391x over previous
//
#include <hip/hip_runtime.h>

typedef float f4 __attribute__((ext_vector_type(4)));
typedef float f32x4 __attribute__((ext_vector_type(4)));
typedef short s16x8 __attribute__((ext_vector_type(8)));

// MFMA GEMM with NO LDS in the main loop and NO cross-lane reduction.
// Block = 4 waves = one 32-token group; wave w owns k-quarter [w*256,+256).
// A-frag (tokens) loaded DIRECTLY from global: lane l = token (l&15),
// 8 contiguous k at (l>>4)*8 -- 64 lanes cover 16 full 128B lines/pair
// (verified layout: R6's LDS-staged A used identical lane->cell math).
// B-frag (weights, experts padded 9->16 with zeros) held bf16 in 32 VGPRs
// per wave. 16 MFMAs/wave accumulate the k-reduction in the matrix pipe.
// Epilogue: 4 partial C's combined via 8KB LDS, one barrier, 32 parallel
// softmaxes. Total regs ~110 -> 4-5 waves/SIMD HW cap (vs 2 for the
// 144-reg weight-resident family, which is why R4/R8/R10 plateaued).

#define TPB 32   // tokens per block

__device__ __forceinline__ unsigned short f2bf(float x) {  // RNE fp32->bf16
  unsigned u = __float_as_uint(x);
  unsigned r = u + 0x7FFF + ((u >> 16) & 1);
  return (unsigned short)(r >> 16);
}

__device__ __forceinline__ s16x8 pack8(f4 a, f4 b) {
  s16x8 h;
  h[0] = (short)f2bf(a.x); h[1] = (short)f2bf(a.y);
  h[2] = (short)f2bf(a.z); h[3] = (short)f2bf(a.w);
  h[4] = (short)f2bf(b.x); h[5] = (short)f2bf(b.y);
  h[6] = (short)f2bf(b.z); h[7] = (short)f2bf(b.w);
  return h;
}

__global__ __launch_bounds__(256)
void moa_mfma2(const float* __restrict__ tok,
               const float* __restrict__ Wq,
               const float* __restrict__ Wk,
               const float* __restrict__ Wv,
               float* __restrict__ out) {
  __shared__ float clds[4 * 512];                 // 8 KB: [wave][32 tok][16 col]
  const int tid  = threadIdx.x;
  const int wv   = tid >> 6;
  const int lane = tid & 63;
  const int n    = lane & 15;                     // A: token row / B: expert col
  const int kg   = lane >> 4;                     // k-group of 8
  const int kq   = wv * 256;                      // wave's k-quarter

  // ---- B-frags: this wave's weight quarter, bf16, 8 steps x 4 dwords ----
  const float* wrow = (n < 3) ? (Wq + n * 1024)
                    : (n < 6) ? (Wk + (n - 3) * 1024)
                    : (n < 9) ? (Wv + (n - 6) * 1024) : Wq;
  const bool wvalid = (n < 9);
  s16x8 bfrag[8];
#pragma unroll
  for (int s = 0; s < 8; ++s) {
    const float* p = wrow + kq + s * 32 + kg * 8;
    f4 wa = wvalid ? *(const f4*)p       : (f4)0.0f;
    f4 wb = wvalid ? *(const f4*)(p + 4) : (f4)0.0f;
    bfrag[s] = pack8(wa, wb);
  }

  // ---- A pointers: two 16-token tiles per wave ----
  const int T0 = blockIdx.x * TPB;
  const float* ap0 = tok + (size_t)(T0 + n) * 1024 + kq + kg * 8;
  const float* ap1 = ap0 + 16 * 1024;

  f32x4 acc0 = {0.f, 0.f, 0.f, 0.f}, acc1 = {0.f, 0.f, 0.f, 0.f};

  // ---- 3-slot ring, prefetch depth 2 (16KB/wave in flight) ----
  f4 r0[3][2], r1[3][2];
#pragma unroll
  for (int s = 0; s < 2; ++s) {
    r0[s][0] = *(const f4*)(ap0 + s * 32);
    r0[s][1] = *(const f4*)(ap0 + s * 32 + 4);
    r1[s][0] = *(const f4*)(ap1 + s * 32);
    r1[s][1] = *(const f4*)(ap1 + s * 32 + 4);
  }

#pragma unroll
  for (int s = 0; s < 8; ++s) {
    const int cs = s % 3, ns = (s + 2) % 3;       // compile-time after unroll
    if (s < 6) {
      r0[ns][0] = *(const f4*)(ap0 + (s + 2) * 32);
      r0[ns][1] = *(const f4*)(ap0 + (s + 2) * 32 + 4);
      r1[ns][0] = *(const f4*)(ap1 + (s + 2) * 32);
      r1[ns][1] = *(const f4*)(ap1 + (s + 2) * 32 + 4);
    }
    s16x8 a0 = pack8(r0[cs][0], r0[cs][1]);
    s16x8 a1 = pack8(r1[cs][0], r1[cs][1]);
    acc0 = __builtin_amdgcn_mfma_f32_16x16x32_bf16(a0, bfrag[s], acc0, 0, 0, 0);
    acc1 = __builtin_amdgcn_mfma_f32_16x16x32_bf16(a1, bfrag[s], acc1, 0, 0, 0);
  }

  // ---- combine 4 k-quarter partials via LDS ----
#pragma unroll
  for (int i = 0; i < 4; ++i) {
    const int row = kg * 4 + i;                    // token-in-tile (C layout, R6-verified)
    clds[wv * 512 + row * 16 + n]        = acc0[i];
    clds[wv * 512 + (16 + row) * 16 + n] = acc1[i];
  }
  __syncthreads();

  // ---- 32 parallel softmaxes (threads 0..31, one token each) ----
  if (tid < TPB) {
    float r[9];
#pragma unroll
    for (int j = 0; j < 9; ++j)
      r[j] = (clds[tid * 16 + j] + clds[512 + tid * 16 + j]) +
             (clds[1024 + tid * 16 + j] + clds[1536 + tid * 16 + j]);
    // q=r[0..2], k=r[3..5], v=r[6..8]
    float lg[3];
#pragma unroll
    for (int e = 0; e < 3; ++e) {
      float e0 = __expf(r[e] * r[3]);
      float e1 = __expf(r[e] * r[4]);
      float e2 = __expf(r[e] * r[5]);
      float den = (e0 + e1) + e2;
      float num = e0 * r[6] + e1 * r[7] + e2 * r[8];
      lg[e] = num * __builtin_amdgcn_rcpf(den);
    }
    float u0 = __expf(lg[0]);
    float u1 = __expf(lg[1]);
    float u2 = __expf(lg[2]);
    float rs = __builtin_amdgcn_rcpf((u0 + u1) + u2);
    float* op = out + (size_t)(T0 + tid) * 3;
    op[0] = u0 * rs;
    op[1] = u1 * rs;
    op[2] = u2 * rs;
  }
}

extern "C" void kernel_launch(void* const* d_in, const int* in_sizes, int n_in,
                              void* d_out, int out_size, void* d_ws, size_t ws_size,
                              hipStream_t stream) {
  const float* tok = (const float*)d_in[0];
  const float* Wq  = (const float*)d_in[1];
  const float* Wk  = (const float*)d_in[2];
  const float* Wv  = (const float*)d_in[3];
  float* out = (float*)d_out;

  const int n_tokens = in_sizes[0] / 1024;   // 32768
  const int blocks   = n_tokens / TPB;       // 1024

  hipLaunchKernelGGL(moa_mfma2, dim3(blocks), dim3(256), 0, stream,
                     tok, Wq, Wk, Wv, out);
}